// Round 1
// baseline (282.703 us; speedup 1.0000x reference)
//
#include <hip/hip_runtime.h>
#include <math.h>

#define IMG_H 576
#define IMG_W 640
#define IMG_HW (IMG_H * IMG_W)
#define BIGF 1e10f
#define EPSF 1e-5f

// d_out layout (floats):
//   [0,       HW)      depth_image
//   [HW,      4*HW)    color_image   (H,W,3)
//   [4*HW,    5*HW)    Imweights_image
//   [5*HW,    6*HW)    weight_image
//   [6*HW,    6*HW+N)  is_visible (0/1)
//
// d_ws layout:
//   [0,   HW)  unsigned int  depth z-buffer (float bits; positive => uint order == float order)
//   [HW, 2*HW) float         patch_min (5x5 min filter of depth)

__global__ void init_kernel(unsigned int* depth_bits, float* out) {
    int i = blockIdx.x * blockDim.x + threadIdx.x;
    if (i < IMG_HW) depth_bits[i] = __float_as_uint(BIGF);
    if (i < 5 * IMG_HW) out[IMG_HW + i] = 0.0f;  // zero color + imw + weight accum images
}

__global__ void zbuf_kernel(const float* __restrict__ pts, const int* __restrict__ mask,
                            unsigned int* depth_bits, int N) {
    int n = blockIdx.x * blockDim.x + threadIdx.x;
    if (n >= N) return;
    float x = pts[3 * n + 0];
    float y = pts[3 * n + 1];
    float z = pts[3 * n + 2];
    int px = (int)floorf(x);
    int py = (int)floorf(y);
    bool valid = (px >= 0) && (px < IMG_W) && (py >= 0) && (py < IMG_H) && (mask[n] > 0);
    if (valid) {
        atomicMin(&depth_bits[py * IMG_W + px], __float_as_uint(z));
    }
}

__global__ void patchmin_kernel(const unsigned int* __restrict__ depth_bits,
                                float* __restrict__ patch_min,
                                float* __restrict__ depth_image) {
    int p = blockIdx.x * blockDim.x + threadIdx.x;
    if (p >= IMG_HW) return;
    int x = p % IMG_W;
    int y = p / IMG_W;
    float d0 = __uint_as_float(depth_bits[p]);
    depth_image[p] = (d0 >= BIGF) ? 0.0f : d0;
    int y0 = max(y - 2, 0), y1 = min(y + 2, IMG_H - 1);
    int x0 = max(x - 2, 0), x1 = min(x + 2, IMG_W - 1);
    float pm = BIGF;
    for (int yy = y0; yy <= y1; ++yy) {
        const unsigned int* row = depth_bits + yy * IMG_W;
        for (int xx = x0; xx <= x1; ++xx) {
            pm = fminf(pm, __uint_as_float(row[xx]));
        }
    }
    patch_min[p] = pm;
}

__global__ void splat_kernel(const float* __restrict__ pts, const float* __restrict__ color,
                             const float* __restrict__ imw, const int* __restrict__ mask,
                             const float* __restrict__ thr,
                             const float* __restrict__ patch_min,
                             float* out, int N) {
    int n = blockIdx.x * blockDim.x + threadIdx.x;
    if (n >= N) return;
    float x = pts[3 * n + 0];
    float y = pts[3 * n + 1];
    float z = pts[3 * n + 2];
    int px = (int)floorf(x);
    int py = (int)floorf(y);
    bool valid = (px >= 0) && (px < IMG_W) && (py >= 0) && (py < IMG_H) && (mask[n] > 0);
    bool vis = false;
    if (valid) {
        float pm = patch_min[py * IMG_W + px];
        vis = (z <= pm + thr[0]);
    }
    out[6 * IMG_HW + n] = vis ? 1.0f : 0.0f;
    if (!vis) return;

    float cr = color[3 * n + 0];
    float cg = color[3 * n + 1];
    float cb = color[3 * n + 2];
    float wv = imw[n];

    float* colimg = out + IMG_HW;          // [H,W,3]
    float* imwimg = out + 4 * IMG_HW;      // [H,W]
    float* wimg   = out + 5 * IMG_HW;      // [H,W]

    for (int oy = -3; oy <= 3; ++oy) {
        int sy = py + oy;
        if (sy < 0 || sy >= IMG_H) continue;
        float dy = (float)sy + 0.5f - y;
        for (int ox = -3; ox <= 3; ++ox) {
            int sx = px + ox;
            if (sx < 0 || sx >= IMG_W) continue;
            float dx = (float)sx + 0.5f - x;
            float w = 1.0f / (dx * dx + dy * dy + EPSF);
            int p = sy * IMG_W + sx;
            atomicAdd(&wimg[p], w);
            atomicAdd(&colimg[3 * p + 0], w * cr);
            atomicAdd(&colimg[3 * p + 1], w * cg);
            atomicAdd(&colimg[3 * p + 2], w * cb);
            atomicAdd(&imwimg[p], w * wv);
        }
    }
}

extern "C" void kernel_launch(void* const* d_in, const int* in_sizes, int n_in,
                              void* d_out, int out_size, void* d_ws, size_t ws_size,
                              hipStream_t stream) {
    const float* pts   = (const float*)d_in[0];   // [B,N,3]
    const float* color = (const float*)d_in[1];   // [B,N,3]
    const float* imw   = (const float*)d_in[2];   // [B,N,1]
    const int*   mask  = (const int*)d_in[3];     // [B,N]
    const float* thr   = (const float*)d_in[4];   // [1]

    int N = in_sizes[3];  // mask element count == B*N, B == 1

    unsigned int* depth_bits = (unsigned int*)d_ws;
    float* patch_min = (float*)d_ws + IMG_HW;
    float* out = (float*)d_out;

    const int B = 256;
    init_kernel<<<(5 * IMG_HW + B - 1) / B, B, 0, stream>>>(depth_bits, out);
    zbuf_kernel<<<(N + B - 1) / B, B, 0, stream>>>(pts, mask, depth_bits, N);
    patchmin_kernel<<<(IMG_HW + B - 1) / B, B, 0, stream>>>(depth_bits, patch_min,
                                                            out /* depth_image at offset 0 */);
    splat_kernel<<<(N + B - 1) / B, B, 0, stream>>>(pts, color, imw, mask, thr,
                                                    patch_min, out, N);
}

// Round 3
// 153.357 us; speedup vs baseline: 1.8434x; 1.8434x over previous
//
#include <hip/hip_runtime.h>
#include <math.h>

#define IMG_H 576
#define IMG_W 640
#define IMG_HW (IMG_H * IMG_W)
#define BIGF 1e10f
#define EPSF 1e-5f

#define TS 16                 // tile size (pixels)
#define TX (IMG_W / TS)       // 40 tiles in x
#define TY (IMG_H / TS)       // 36 tiles in y
#define NT (TX * TY)          // 1440 tiles

// d_out layout (floats):
//   [0,       HW)      depth_image
//   [HW,      4*HW)    color_image   (H,W,3)
//   [4*HW,    5*HW)    Imweights_image
//   [5*HW,    6*HW)    weight_image
//   [6*HW,    6*HW+N)  is_visible (0/1)
//
// d_ws layout (4-byte words):
//   [0,        HW)            uint  depth z-buffer (float bits; z>0 => uint order == float order)
//   [HW,       2*HW)          f32   patch_min (5x5 min filter of depth)
//   [2*HW,          +NT)      uint  per-tile membership counters
//   [2*HW+NT,       +NT)      uint  per-tile entry offsets (exclusive scan)
//   [2*HW+2*NT,     +NT)      uint  per-tile fill cursors
//   [2*HW+3*NT, +cap)         uint  tile point-index lists (entries)
//                                   -- rowmin (HW f32) ALIASES the entries
//                                      region: rowmin is dead before fill runs.

__global__ void init_kernel(unsigned int* depth_bits, unsigned int* counters) {
    int i = blockIdx.x * blockDim.x + threadIdx.x;
    if (i < IMG_HW) depth_bits[i] = __float_as_uint(BIGF);
    if (i < NT) counters[i] = 0u;
}

__global__ void zbuf_count_kernel(const float* __restrict__ pts, const int* __restrict__ mask,
                                  unsigned int* depth_bits, unsigned int* counters, int N) {
    int n = blockIdx.x * blockDim.x + threadIdx.x;
    if (n >= N) return;
    float x = pts[3 * n + 0];
    float y = pts[3 * n + 1];
    float z = pts[3 * n + 2];
    int px = (int)floorf(x);
    int py = (int)floorf(y);
    bool valid = (px >= 0) && (px < IMG_W) && (py >= 0) && (py < IMG_H) && (mask[n] > 0);
    if (!valid) return;
    atomicMin(&depth_bits[py * IMG_W + px], __float_as_uint(z));
    // count tile memberships of the (image-clipped) 7x7 splat window
    int xs0 = max(px - 3, 0), xs1 = min(px + 3, IMG_W - 1);
    int ys0 = max(py - 3, 0), ys1 = min(py + 3, IMG_H - 1);
    int tx0 = xs0 >> 4, tx1 = xs1 >> 4;
    int ty0 = ys0 >> 4, ty1 = ys1 >> 4;
    for (int ty = ty0; ty <= ty1; ++ty)
        for (int tx = tx0; tx <= tx1; ++tx)
            atomicAdd(&counters[ty * TX + tx], 1u);
}

// horizontal 5-tap min (range-clip == SAME pad with BIG) + depth_image finalize
__global__ void rowmin_kernel(const unsigned int* __restrict__ depth_bits,
                              float* __restrict__ rowmin,
                              float* __restrict__ depth_image) {
    int p = blockIdx.x * blockDim.x + threadIdx.x;
    if (p >= IMG_HW) return;
    int x = p % IMG_W;
    float d0 = __uint_as_float(depth_bits[p]);
    depth_image[p] = (d0 >= BIGF) ? 0.0f : d0;
    int x0 = max(x - 2, 0), x1 = min(x + 2, IMG_W - 1);
    const unsigned int* row = depth_bits + (p - x);
    float m = BIGF;
    for (int xx = x0; xx <= x1; ++xx) m = fminf(m, __uint_as_float(row[xx]));
    rowmin[p] = m;
}

// vertical 5-tap min of rowmin -> patch_min
__global__ void colmin_kernel(const float* __restrict__ rowmin, float* __restrict__ patch_min) {
    int p = blockIdx.x * blockDim.x + threadIdx.x;
    if (p >= IMG_HW) return;
    int x = p % IMG_W;
    int y = p / IMG_W;
    int y0 = max(y - 2, 0), y1 = min(y + 2, IMG_H - 1);
    float m = BIGF;
    for (int yy = y0; yy <= y1; ++yy) m = fminf(m, rowmin[yy * IMG_W + x]);
    patch_min[p] = m;
}

// single-block exclusive scan of NT counters -> offsets, cursors
__global__ void scan_kernel(const unsigned int* __restrict__ counters,
                            unsigned int* __restrict__ offsets,
                            unsigned int* __restrict__ cursors) {
    __shared__ unsigned int partial[256];
    int tid = threadIdx.x;
    const int CH = (NT + 255) / 256;  // 6
    unsigned int vals[CH];
    unsigned int s = 0;
    for (int i = 0; i < CH; ++i) {
        int idx = tid * CH + i;
        unsigned int c = (idx < NT) ? counters[idx] : 0u;
        vals[i] = s;
        s += c;
    }
    partial[tid] = s;
    __syncthreads();
    for (int off = 1; off < 256; off <<= 1) {
        unsigned int t = (tid >= off) ? partial[tid - off] : 0u;
        __syncthreads();
        partial[tid] += t;
        __syncthreads();
    }
    unsigned int base = (tid > 0) ? partial[tid - 1] : 0u;
    for (int i = 0; i < CH; ++i) {
        int idx = tid * CH + i;
        if (idx < NT) {
            unsigned int o = base + vals[i];
            offsets[idx] = o;
            cursors[idx] = o;
        }
    }
}

// visibility for all points; append visible points to overlapping tile lists
__global__ void fill_kernel(const float* __restrict__ pts, const int* __restrict__ mask,
                            const float* __restrict__ thr,
                            const float* __restrict__ patch_min,
                            unsigned int* __restrict__ cursors,
                            unsigned int* __restrict__ entries,
                            float* __restrict__ out_vis, int N, unsigned int entry_cap) {
    int n = blockIdx.x * blockDim.x + threadIdx.x;
    if (n >= N) return;
    float x = pts[3 * n + 0];
    float y = pts[3 * n + 1];
    float z = pts[3 * n + 2];
    int px = (int)floorf(x);
    int py = (int)floorf(y);
    bool valid = (px >= 0) && (px < IMG_W) && (py >= 0) && (py < IMG_H) && (mask[n] > 0);
    bool vis = false;
    if (valid) {
        float pm = patch_min[py * IMG_W + px];
        vis = (z <= pm + thr[0]);
    }
    out_vis[n] = vis ? 1.0f : 0.0f;
    if (!vis) return;
    int xs0 = max(px - 3, 0), xs1 = min(px + 3, IMG_W - 1);
    int ys0 = max(py - 3, 0), ys1 = min(py + 3, IMG_H - 1);
    int tx0 = xs0 >> 4, tx1 = xs1 >> 4;
    int ty0 = ys0 >> 4, ty1 = ys1 >> 4;
    for (int ty = ty0; ty <= ty1; ++ty)
        for (int tx = tx0; tx <= tx1; ++tx) {
            unsigned int idx = atomicAdd(&cursors[ty * TX + tx], 1u);
            if (idx < entry_cap) entries[idx] = (unsigned int)n;  // defensive: no OOB write
        }
}

// one workgroup per 16x16 tile: LDS-accumulate taps, plain-store the core
__global__ void __launch_bounds__(256)
tile_splat_kernel(const float* __restrict__ pts, const float* __restrict__ color,
                  const float* __restrict__ imw,
                  const unsigned int* __restrict__ offsets,
                  const unsigned int* __restrict__ cursors,
                  const unsigned int* __restrict__ entries,
                  float* __restrict__ out, unsigned int entry_cap) {
    __shared__ float accW[TS * TS];
    __shared__ float accI[TS * TS];
    __shared__ float accR[TS * TS];
    __shared__ float accG[TS * TS];
    __shared__ float accB[TS * TS];
    int tid = threadIdx.x;
    if (tid < TS * TS) {
        accW[tid] = 0.0f; accI[tid] = 0.0f;
        accR[tid] = 0.0f; accG[tid] = 0.0f; accB[tid] = 0.0f;
    }
    __syncthreads();

    int tile = blockIdx.x;
    int tx0p = (tile % TX) * TS;
    int ty0p = (tile / TX) * TS;
    unsigned int base = offsets[tile];
    unsigned int end = min(cursors[tile], entry_cap);
    unsigned int count = (end > base) ? (end - base) : 0u;

    for (unsigned int e = tid; e < count; e += blockDim.x) {
        int n = (int)entries[base + e];
        float x = pts[3 * n + 0];
        float y = pts[3 * n + 1];
        int px = (int)floorf(x);
        int py = (int)floorf(y);
        float cr = color[3 * n + 0];
        float cg = color[3 * n + 1];
        float cb = color[3 * n + 2];
        float wv = imw[n];
        int sy0 = max(py - 3, ty0p), sy1 = min(py + 3, ty0p + TS - 1);
        int sx0 = max(px - 3, tx0p), sx1 = min(px + 3, tx0p + TS - 1);
        for (int sy = sy0; sy <= sy1; ++sy) {
            float dy = (float)sy + 0.5f - y;
            int ly = sy - ty0p;
            for (int sx = sx0; sx <= sx1; ++sx) {
                float dx = (float)sx + 0.5f - x;
                float w = 1.0f / (dx * dx + dy * dy + EPSF);
                int l = ly * TS + (sx - tx0p);
                atomicAdd(&accW[l], w);
                atomicAdd(&accI[l], w * wv);
                atomicAdd(&accR[l], w * cr);
                atomicAdd(&accG[l], w * cg);
                atomicAdd(&accB[l], w * cb);
            }
        }
    }
    __syncthreads();

    float* colimg = out + IMG_HW;
    float* imwimg = out + 4 * IMG_HW;
    float* wimg   = out + 5 * IMG_HW;
    if (tid < TS * TS) {
        int ly = tid / TS, lx = tid % TS;
        int p = (ty0p + ly) * IMG_W + tx0p + lx;
        wimg[p]   = accW[tid];
        imwimg[p] = accI[tid];
        colimg[3 * p + 0] = accR[tid];
        colimg[3 * p + 1] = accG[tid];
        colimg[3 * p + 2] = accB[tid];
    }
}

extern "C" void kernel_launch(void* const* d_in, const int* in_sizes, int n_in,
                              void* d_out, int out_size, void* d_ws, size_t ws_size,
                              hipStream_t stream) {
    const float* pts   = (const float*)d_in[0];   // [B,N,3]
    const float* color = (const float*)d_in[1];   // [B,N,3]
    const float* imw   = (const float*)d_in[2];   // [B,N,1]
    const int*   mask  = (const int*)d_in[3];     // [B,N]
    const float* thr   = (const float*)d_in[4];   // [1]

    int N = in_sizes[3];  // B*N, B == 1

    unsigned int* ws_u = (unsigned int*)d_ws;
    unsigned int* depth_bits = ws_u;                       // HW
    float*        patch_min  = (float*)(ws_u + IMG_HW);    // HW
    unsigned int* counters   = ws_u + 2 * IMG_HW;          // NT
    unsigned int* offsets    = counters + NT;              // NT
    unsigned int* cursors    = offsets + NT;               // NT
    unsigned int* entries    = cursors + NT;               // cap words
    float*        rowmin_buf = (float*)entries;            // HW, dead before fill

    // entry capacity from what's actually available in d_ws
    size_t used_words = (size_t)2 * IMG_HW + 3 * NT;
    size_t avail_words = (ws_size / 4 > used_words) ? (ws_size / 4 - used_words) : 0;
    unsigned int want = (unsigned int)(4 * (size_t)N);
    unsigned int entry_cap = (avail_words < want) ? (unsigned int)avail_words : want;

    float* out = (float*)d_out;
    float* out_vis = out + 6 * IMG_HW;

    const int B = 256;
    init_kernel<<<(IMG_HW + B - 1) / B, B, 0, stream>>>(depth_bits, counters);
    zbuf_count_kernel<<<(N + B - 1) / B, B, 0, stream>>>(pts, mask, depth_bits, counters, N);
    rowmin_kernel<<<(IMG_HW + B - 1) / B, B, 0, stream>>>(depth_bits, rowmin_buf, out);
    colmin_kernel<<<(IMG_HW + B - 1) / B, B, 0, stream>>>(rowmin_buf, patch_min);
    scan_kernel<<<1, 256, 0, stream>>>(counters, offsets, cursors);
    fill_kernel<<<(N + B - 1) / B, B, 0, stream>>>(pts, mask, thr, patch_min, cursors,
                                                   entries, out_vis, N, entry_cap);
    tile_splat_kernel<<<NT, 256, 0, stream>>>(pts, color, imw, offsets, cursors, entries,
                                              out, entry_cap);
}

// Round 4
// 111.564 us; speedup vs baseline: 2.5340x; 1.3746x over previous
//
#include <hip/hip_runtime.h>
#include <math.h>

#define IMG_H 576
#define IMG_W 640
#define IMG_HW (IMG_H * IMG_W)
#define BIGF 1e10f
#define EPSF 1e-5f

#define TS 16                 // splat tile size (pixels)
#define TX (IMG_W / TS)       // 40
#define TY (IMG_H / TS)       // 36
#define NT (TX * TY)          // 1440 tiles
#define CAP 512               // fixed per-tile entry capacity (expected ~42, Poisson tail nil)

// patchmin block geometry: 32x8 pixels per 256-thread block, halo 2
#define PBX 32
#define PBY 8
#define LW (PBX + 4)          // 36
#define LH (PBY + 4)          // 12

// d_out layout (floats):
//   [0,       HW)      depth_image
//   [HW,      4*HW)    color_image   (H,W,3)
//   [4*HW,    5*HW)    Imweights_image
//   [5*HW,    6*HW)    weight_image
//   [6*HW,    6*HW+N)  is_visible (0/1)
//
// d_ws layout (4-byte words):
//   [0,        HW)        uint  depth z-buffer (float bits; z>0 => uint order == float order)
//   [HW,       2*HW)      f32   patch_min (5x5 min filter of depth)
//   [2*HW,     +NT)       uint  per-tile counters
//   [2*HW+NT,  +NT*CAP)   uint  fixed-stride per-tile point-index lists

__global__ void init_kernel(unsigned int* depth_bits, unsigned int* counters) {
    int i = blockIdx.x * blockDim.x + threadIdx.x;
    if (i < IMG_HW) depth_bits[i] = __float_as_uint(BIGF);
    if (i < NT) counters[i] = 0u;
}

// pure z-buffer scatter-min
__global__ void zbuf_kernel(const float* __restrict__ pts, const int* __restrict__ mask,
                            unsigned int* depth_bits, int N) {
    int n = blockIdx.x * blockDim.x + threadIdx.x;
    if (n >= N) return;
    float x = pts[3 * n + 0];
    float y = pts[3 * n + 1];
    float z = pts[3 * n + 2];
    int px = (int)floorf(x);
    int py = (int)floorf(y);
    if (px >= 0 && px < IMG_W && py >= 0 && py < IMG_H && mask[n] > 0)
        atomicMin(&depth_bits[py * IMG_W + px], __float_as_uint(z));
}

// fused 5x5 min filter (SAME pad with BIG) via LDS tile + depth_image finalize
__global__ void __launch_bounds__(256)
patchmin_kernel(const unsigned int* __restrict__ depth_bits,
                float* __restrict__ patch_min,
                float* __restrict__ depth_image) {
    __shared__ float lds[LH * LW];
    int bx = (blockIdx.x % (IMG_W / PBX)) * PBX;
    int by = (blockIdx.x / (IMG_W / PBX)) * PBY;
    int tid = threadIdx.x;
    // cooperative halo load: LH*LW = 432 elements, 256 threads
    for (int i = tid; i < LH * LW; i += 256) {
        int gx = bx - 2 + (i % LW);
        int gy = by - 2 + (i / LW);
        float v = BIGF;
        if (gx >= 0 && gx < IMG_W && gy >= 0 && gy < IMG_H)
            v = __uint_as_float(depth_bits[gy * IMG_W + gx]);
        lds[i] = v;
    }
    __syncthreads();
    int lx = tid & (PBX - 1);
    int ly = tid >> 5;
    float m = BIGF;
    #pragma unroll
    for (int dy = 0; dy < 5; ++dy) {
        const float* row = lds + (ly + dy) * LW + lx;
        #pragma unroll
        for (int dx = 0; dx < 5; ++dx) m = fminf(m, row[dx]);
    }
    int p = (by + ly) * IMG_W + bx + lx;
    patch_min[p] = m;
    float d0 = lds[(ly + 2) * LW + lx + 2];
    depth_image[p] = (d0 >= BIGF) ? 0.0f : d0;
}

// visibility + direct append of visible points to fixed-stride tile lists
__global__ void vis_fill_kernel(const float* __restrict__ pts, const int* __restrict__ mask,
                                const float* __restrict__ thr,
                                const float* __restrict__ patch_min,
                                unsigned int* __restrict__ counters,
                                unsigned int* __restrict__ entries,
                                float* __restrict__ out_vis, int N) {
    int n = blockIdx.x * blockDim.x + threadIdx.x;
    if (n >= N) return;
    float x = pts[3 * n + 0];
    float y = pts[3 * n + 1];
    float z = pts[3 * n + 2];
    int px = (int)floorf(x);
    int py = (int)floorf(y);
    bool valid = (px >= 0) && (px < IMG_W) && (py >= 0) && (py < IMG_H) && (mask[n] > 0);
    bool vis = false;
    if (valid) {
        float pm = patch_min[py * IMG_W + px];
        vis = (z <= pm + thr[0]);
    }
    out_vis[n] = vis ? 1.0f : 0.0f;
    if (!vis) return;
    int xs0 = max(px - 3, 0), xs1 = min(px + 3, IMG_W - 1);
    int ys0 = max(py - 3, 0), ys1 = min(py + 3, IMG_H - 1);
    int tx0 = xs0 >> 4, tx1 = xs1 >> 4;
    int ty0 = ys0 >> 4, ty1 = ys1 >> 4;
    for (int ty = ty0; ty <= ty1; ++ty)
        for (int tx = tx0; tx <= tx1; ++tx) {
            int t = ty * TX + tx;
            unsigned int idx = atomicAdd(&counters[t], 1u);
            if (idx < CAP) entries[t * CAP + idx] = (unsigned int)n;  // defensive clamp
        }
}

// one workgroup per 16x16 tile: LDS-accumulate taps, plain-store the core
__global__ void __launch_bounds__(256)
tile_splat_kernel(const float* __restrict__ pts, const float* __restrict__ color,
                  const float* __restrict__ imw,
                  const unsigned int* __restrict__ counters,
                  const unsigned int* __restrict__ entries,
                  float* __restrict__ out) {
    __shared__ float accW[TS * TS];
    __shared__ float accI[TS * TS];
    __shared__ float accR[TS * TS];
    __shared__ float accG[TS * TS];
    __shared__ float accB[TS * TS];
    int tid = threadIdx.x;
    if (tid < TS * TS) {
        accW[tid] = 0.0f; accI[tid] = 0.0f;
        accR[tid] = 0.0f; accG[tid] = 0.0f; accB[tid] = 0.0f;
    }
    __syncthreads();

    int tile = blockIdx.x;
    int tx0p = (tile % TX) * TS;
    int ty0p = (tile / TX) * TS;
    unsigned int count = min(counters[tile], (unsigned int)CAP);
    const unsigned int* list = entries + tile * CAP;

    for (unsigned int e = tid; e < count; e += blockDim.x) {
        int n = (int)list[e];
        float x = pts[3 * n + 0];
        float y = pts[3 * n + 1];
        int px = (int)floorf(x);
        int py = (int)floorf(y);
        float cr = color[3 * n + 0];
        float cg = color[3 * n + 1];
        float cb = color[3 * n + 2];
        float wv = imw[n];
        int sy0 = max(py - 3, ty0p), sy1 = min(py + 3, ty0p + TS - 1);
        int sx0 = max(px - 3, tx0p), sx1 = min(px + 3, tx0p + TS - 1);
        for (int sy = sy0; sy <= sy1; ++sy) {
            float dy = (float)sy + 0.5f - y;
            int ly = sy - ty0p;
            for (int sx = sx0; sx <= sx1; ++sx) {
                float dx = (float)sx + 0.5f - x;
                float w = 1.0f / (dx * dx + dy * dy + EPSF);
                int l = ly * TS + (sx - tx0p);
                atomicAdd(&accW[l], w);
                atomicAdd(&accI[l], w * wv);
                atomicAdd(&accR[l], w * cr);
                atomicAdd(&accG[l], w * cg);
                atomicAdd(&accB[l], w * cb);
            }
        }
    }
    __syncthreads();

    float* colimg = out + IMG_HW;
    float* imwimg = out + 4 * IMG_HW;
    float* wimg   = out + 5 * IMG_HW;
    if (tid < TS * TS) {
        int ly = tid / TS, lx = tid % TS;
        int p = (ty0p + ly) * IMG_W + tx0p + lx;
        wimg[p]   = accW[tid];
        imwimg[p] = accI[tid];
        colimg[3 * p + 0] = accR[tid];
        colimg[3 * p + 1] = accG[tid];
        colimg[3 * p + 2] = accB[tid];
    }
}

extern "C" void kernel_launch(void* const* d_in, const int* in_sizes, int n_in,
                              void* d_out, int out_size, void* d_ws, size_t ws_size,
                              hipStream_t stream) {
    const float* pts   = (const float*)d_in[0];   // [B,N,3]
    const float* color = (const float*)d_in[1];   // [B,N,3]
    const float* imw   = (const float*)d_in[2];   // [B,N,1]
    const int*   mask  = (const int*)d_in[3];     // [B,N]
    const float* thr   = (const float*)d_in[4];   // [1]

    int N = in_sizes[3];  // B*N, B == 1

    unsigned int* ws_u = (unsigned int*)d_ws;
    unsigned int* depth_bits = ws_u;                       // HW
    float*        patch_min  = (float*)(ws_u + IMG_HW);    // HW
    unsigned int* counters   = ws_u + 2 * IMG_HW;          // NT
    unsigned int* entries    = counters + NT;              // NT*CAP

    float* out = (float*)d_out;
    float* out_vis = out + 6 * IMG_HW;

    const int B = 256;
    init_kernel<<<(IMG_HW + B - 1) / B, B, 0, stream>>>(depth_bits, counters);
    zbuf_kernel<<<(N + B - 1) / B, B, 0, stream>>>(pts, mask, depth_bits, N);
    patchmin_kernel<<<(IMG_W / PBX) * (IMG_H / PBY), 256, 0, stream>>>(depth_bits, patch_min, out);
    vis_fill_kernel<<<(N + B - 1) / B, B, 0, stream>>>(pts, mask, thr, patch_min,
                                                       counters, entries, out_vis, N);
    tile_splat_kernel<<<NT, 256, 0, stream>>>(pts, color, imw, counters, entries, out);
}

// Round 5
// 94.038 us; speedup vs baseline: 3.0063x; 1.1864x over previous
//
#include <hip/hip_runtime.h>
#include <math.h>

#define IMG_H 576
#define IMG_W 640
#define IMG_HW (IMG_H * IMG_W)
#define BIGF 1e10f
#define EPSF 1e-5f

#define TS 16                 // splat tile size (pixels); 256 threads = 1 thread/pixel
#define TX (IMG_W / TS)       // 40
#define TY (IMG_H / TS)       // 36
#define NT (TX * TY)          // 1440 tiles
#define CAP 512               // per-tile entry capacity (expected ~20-40; clamped defensively)

// patchmin block geometry: 32x8 pixels per 256-thread block, halo 2
#define PBX 32
#define PBY 8
#define LW (PBX + 4)          // 36
#define LH (PBY + 4)          // 12

// d_out layout (floats):
//   [0,       HW)      depth_image
//   [HW,      4*HW)    color_image   (H,W,3)
//   [4*HW,    5*HW)    Imweights_image
//   [5*HW,    6*HW)    weight_image
//   [6*HW,    6*HW+N)  is_visible (0/1)
//
// d_ws layout (4-byte words):
//   [0,        HW)        uint  depth z-buffer (float bits; z>0 => uint order == float order)
//   [HW,       2*HW)      f32   patch_min (5x5 min filter of depth)
//   [2*HW,     +NT)       uint  per-tile counters
//   [2*HW+NT,  +NT*CAP)   uint  fixed-stride per-tile point-index lists

__global__ void init_kernel(unsigned int* depth_bits, unsigned int* counters) {
    int i = blockIdx.x * blockDim.x + threadIdx.x;
    if (i < IMG_HW) depth_bits[i] = __float_as_uint(BIGF);
    if (i < NT) counters[i] = 0u;
}

// pure z-buffer scatter-min
__global__ void zbuf_kernel(const float* __restrict__ pts, const int* __restrict__ mask,
                            unsigned int* depth_bits, int N) {
    int n = blockIdx.x * blockDim.x + threadIdx.x;
    if (n >= N) return;
    float x = pts[3 * n + 0];
    float y = pts[3 * n + 1];
    float z = pts[3 * n + 2];
    int px = (int)floorf(x);
    int py = (int)floorf(y);
    if (px >= 0 && px < IMG_W && py >= 0 && py < IMG_H && mask[n] > 0)
        atomicMin(&depth_bits[py * IMG_W + px], __float_as_uint(z));
}

// 5x5 min filter (SAME pad with BIG) via LDS tile
__global__ void __launch_bounds__(256)
patchmin_kernel(const unsigned int* __restrict__ depth_bits,
                float* __restrict__ patch_min) {
    __shared__ float lds[LH * LW];
    int bx = (blockIdx.x % (IMG_W / PBX)) * PBX;
    int by = (blockIdx.x / (IMG_W / PBX)) * PBY;
    int tid = threadIdx.x;
    // cooperative halo load: LH*LW = 432 elements, 256 threads
    for (int i = tid; i < LH * LW; i += 256) {
        int gx = bx - 2 + (i % LW);
        int gy = by - 2 + (i / LW);
        float v = BIGF;
        if (gx >= 0 && gx < IMG_W && gy >= 0 && gy < IMG_H)
            v = __uint_as_float(depth_bits[gy * IMG_W + gx]);
        lds[i] = v;
    }
    __syncthreads();
    int lx = tid & (PBX - 1);
    int ly = tid >> 5;
    float m = BIGF;
    #pragma unroll
    for (int dy = 0; dy < 5; ++dy) {
        const float* row = lds + (ly + dy) * LW + lx;
        #pragma unroll
        for (int dx = 0; dx < 5; ++dx) m = fminf(m, row[dx]);
    }
    patch_min[(by + ly) * IMG_W + bx + lx] = m;
}

// visibility + direct append of visible points to fixed-stride tile lists
__global__ void vis_fill_kernel(const float* __restrict__ pts, const int* __restrict__ mask,
                                const float* __restrict__ thr,
                                const float* __restrict__ patch_min,
                                unsigned int* __restrict__ counters,
                                unsigned int* __restrict__ entries,
                                float* __restrict__ out_vis, int N) {
    int n = blockIdx.x * blockDim.x + threadIdx.x;
    if (n >= N) return;
    float x = pts[3 * n + 0];
    float y = pts[3 * n + 1];
    float z = pts[3 * n + 2];
    int px = (int)floorf(x);
    int py = (int)floorf(y);
    bool valid = (px >= 0) && (px < IMG_W) && (py >= 0) && (py < IMG_H) && (mask[n] > 0);
    bool vis = false;
    if (valid) {
        float pm = patch_min[py * IMG_W + px];
        vis = (z <= pm + thr[0]);
    }
    out_vis[n] = vis ? 1.0f : 0.0f;
    if (!vis) return;
    int xs0 = max(px - 3, 0), xs1 = min(px + 3, IMG_W - 1);
    int ys0 = max(py - 3, 0), ys1 = min(py + 3, IMG_H - 1);
    int tx0 = xs0 >> 4, tx1 = xs1 >> 4;
    int ty0 = ys0 >> 4, ty1 = ys1 >> 4;
    for (int ty = ty0; ty <= ty1; ++ty)
        for (int tx = tx0; tx <= tx1; ++tx) {
            int t = ty * TX + tx;
            unsigned int idx = atomicAdd(&counters[t], 1u);
            if (idx < CAP) entries[t * CAP + idx] = (unsigned int)n;  // defensive clamp
        }
}

// GATHER splat: one workgroup per 16x16 tile, one thread per pixel.
// Register accumulation, LDS point staging (broadcast reads), zero atomics.
// Also finalizes depth_image (covers every pixel).
__global__ void __launch_bounds__(256)
tile_splat_kernel(const float* __restrict__ pts, const float* __restrict__ color,
                  const float* __restrict__ imw,
                  const unsigned int* __restrict__ counters,
                  const unsigned int* __restrict__ entries,
                  const unsigned int* __restrict__ depth_bits,
                  float* __restrict__ out) {
    __shared__ float sx_[256], sy_[256], sr_[256], sg_[256], sb_[256], si_[256];
    int tile = blockIdx.x;
    int tx0p = (tile % TX) * TS;
    int ty0p = (tile / TX) * TS;
    int tid = threadIdx.x;
    int lx = tid & (TS - 1);
    int ly = tid >> 4;
    int gx = tx0p + lx;
    int gy = ty0p + ly;
    float pxf = (float)gx + 0.5f;
    float pyf = (float)gy + 0.5f;

    float aW = 0.0f, aI = 0.0f, aR = 0.0f, aG = 0.0f, aB = 0.0f;

    unsigned int count = min(counters[tile], (unsigned int)CAP);
    const unsigned int* list = entries + tile * CAP;

    for (unsigned int base = 0; base < count; base += 256u) {
        unsigned int chunk = min(256u, count - base);
        __syncthreads();  // protect LDS from previous chunk's readers
        if (tid < chunk) {
            int n = (int)list[base + tid];
            sx_[tid] = pts[3 * n + 0];
            sy_[tid] = pts[3 * n + 1];
            sr_[tid] = color[3 * n + 0];
            sg_[tid] = color[3 * n + 1];
            sb_[tid] = color[3 * n + 2];
            si_[tid] = imw[n];
        }
        __syncthreads();
        for (unsigned int e = 0; e < chunk; ++e) {
            float x = sx_[e];
            float y = sy_[e];
            int px = (int)floorf(x);
            int py = (int)floorf(y);
            // does this point's 7x7 window cover pixel (gx,gy)?
            if ((unsigned int)(gx - px + 3) <= 6u && (unsigned int)(gy - py + 3) <= 6u) {
                float dx = pxf - x;
                float dy = pyf - y;
                float w = 1.0f / (dx * dx + dy * dy + EPSF);
                aW += w;
                aI += w * si_[e];
                aR += w * sr_[e];
                aG += w * sg_[e];
                aB += w * sb_[e];
            }
        }
    }

    int p = gy * IMG_W + gx;
    float d0 = __uint_as_float(depth_bits[p]);
    out[p] = (d0 >= BIGF) ? 0.0f : d0;   // depth_image
    float* colimg = out + IMG_HW;
    colimg[3 * p + 0] = aR;
    colimg[3 * p + 1] = aG;
    colimg[3 * p + 2] = aB;
    out[4 * IMG_HW + p] = aI;            // Imweights_image
    out[5 * IMG_HW + p] = aW;            // weight_image
}

extern "C" void kernel_launch(void* const* d_in, const int* in_sizes, int n_in,
                              void* d_out, int out_size, void* d_ws, size_t ws_size,
                              hipStream_t stream) {
    const float* pts   = (const float*)d_in[0];   // [B,N,3]
    const float* color = (const float*)d_in[1];   // [B,N,3]
    const float* imw   = (const float*)d_in[2];   // [B,N,1]
    const int*   mask  = (const int*)d_in[3];     // [B,N]
    const float* thr   = (const float*)d_in[4];   // [1]

    int N = in_sizes[3];  // B*N, B == 1

    unsigned int* ws_u = (unsigned int*)d_ws;
    unsigned int* depth_bits = ws_u;                       // HW
    float*        patch_min  = (float*)(ws_u + IMG_HW);    // HW
    unsigned int* counters   = ws_u + 2 * IMG_HW;          // NT
    unsigned int* entries    = counters + NT;              // NT*CAP

    float* out = (float*)d_out;
    float* out_vis = out + 6 * IMG_HW;

    const int B = 256;
    init_kernel<<<(IMG_HW + B - 1) / B, B, 0, stream>>>(depth_bits, counters);
    zbuf_kernel<<<(N + B - 1) / B, B, 0, stream>>>(pts, mask, depth_bits, N);
    patchmin_kernel<<<(IMG_W / PBX) * (IMG_H / PBY), 256, 0, stream>>>(depth_bits, patch_min);
    vis_fill_kernel<<<(N + B - 1) / B, B, 0, stream>>>(pts, mask, thr, patch_min,
                                                       counters, entries, out_vis, N);
    tile_splat_kernel<<<NT, 256, 0, stream>>>(pts, color, imw, counters, entries,
                                              depth_bits, out);
}